// Round 1
// baseline (25.954 us; speedup 1.0000x reference)
//
#include <hip/hip_runtime.h>
#include <math.h>

// Problem constants (from reference): N=2048 nodes, D=64 dim, B=256 queries.
#define NN 2048
#define DD 64
#define BB 256
#define BLOCK 1024  // 16 waves per block; grid = B = 256 -> 1 block/CU

__global__ __launch_bounds__(BLOCK) void resonance_kernel(
    const int* __restrict__ idx,       // (B,) int32
    const float* __restrict__ ctx,     // (D,)
    const float* __restrict__ W,       // (N, N, D)
    float* __restrict__ out)           // (B, N)
{
    const int b    = blockIdx.x;
    const int tid  = threadIdx.x;
    const int lane = tid & 63;
    const int wave = tid >> 6;            // 0..15

    const int node = idx[b];
    const float* __restrict__ Wb = W + (size_t)node * (NN * DD);

    __shared__ float e_lds[NN];           // 8 KB energies
    __shared__ float red[16];
    __shared__ float bcast;

    // Per-lane context fragment: 16 lanes x float4 cover all D=64.
    const float4 c = reinterpret_cast<const float4*>(ctx)[lane & 15];
    const int sub = lane >> 4;            // which of the 4 rows this wave-iter

    // ---- Phase 1: energies e[n] = dot(W[node,n,:], ctx) ----
    // Each wave handles 4 consecutive rows per iter: one contiguous 1 KB load.
    #pragma unroll 4
    for (int k = 0; k < NN / (4 * 16); ++k) {   // 32 iters
        const int n = 4 * (wave + 16 * k) + sub;
        const float4 v =
            reinterpret_cast<const float4*>(Wb + (size_t)n * DD)[lane & 15];
        float s = v.x * c.x + v.y * c.y + v.z * c.z + v.w * c.w;
        // reduce across the 16 lanes that share this row
        s += __shfl_xor(s, 1);
        s += __shfl_xor(s, 2);
        s += __shfl_xor(s, 4);
        s += __shfl_xor(s, 8);
        if ((lane & 15) == 0) e_lds[n] = s;
    }
    __syncthreads();

    // ---- Phase 2: softmax over n ----
    // Each thread owns n = tid and n = tid + 1024.
    const float e0 = e_lds[tid];
    const float e1 = e_lds[tid + BLOCK];

    // block max
    float m = fmaxf(e0, e1);
    #pragma unroll
    for (int o = 32; o > 0; o >>= 1) m = fmaxf(m, __shfl_xor(m, o));
    if (lane == 0) red[wave] = m;
    __syncthreads();
    if (wave == 0) {
        float t = red[lane & 15];
        #pragma unroll
        for (int o = 8; o > 0; o >>= 1) t = fmaxf(t, __shfl_xor(t, o));
        if (lane == 0) bcast = t;
    }
    __syncthreads();
    const float M = bcast;
    __syncthreads();   // protect red[] reuse

    // exp + block sum
    const float x0 = expf(e0 - M);
    const float x1 = expf(e1 - M);
    float s = x0 + x1;
    #pragma unroll
    for (int o = 32; o > 0; o >>= 1) s += __shfl_xor(s, o);
    if (lane == 0) red[wave] = s;
    __syncthreads();
    if (wave == 0) {
        float t = red[lane & 15];
        #pragma unroll
        for (int o = 8; o > 0; o >>= 1) t += __shfl_xor(t, o);
        if (lane == 0) bcast = t;
    }
    __syncthreads();
    const float inv = 1.0f / bcast;

    float* __restrict__ orow = out + (size_t)b * NN;
    orow[tid]         = x0 * inv;
    orow[tid + BLOCK] = x1 * inv;
}

extern "C" void kernel_launch(void* const* d_in, const int* in_sizes, int n_in,
                              void* d_out, int out_size, void* d_ws, size_t ws_size,
                              hipStream_t stream) {
    const int*   idx = (const int*)d_in[0];    // node_indices (B,)
    const float* ctx = (const float*)d_in[1];  // context_vector (D,)
    const float* W   = (const float*)d_in[2];  // W (N,N,D)
    float*       out = (float*)d_out;          // (B, N)

    resonance_kernel<<<BB, BLOCK, 0, stream>>>(idx, ctx, W, out);
}

// Round 2
// 25.662 us; speedup vs baseline: 1.0114x; 1.0114x over previous
//
#include <hip/hip_runtime.h>
#include <math.h>

// Problem constants (from reference): N=2048 nodes, D=64 dim, B=256 queries.
#define NN 2048
#define DD 64
#define BB 256
#define BLOCK 1024  // 16 waves per block; grid = B = 256 -> 1 block/CU

__global__ __launch_bounds__(BLOCK) void resonance_kernel(
    const int* __restrict__ idx,       // (B,) int32
    const float* __restrict__ ctx,     // (D,)
    const float* __restrict__ W,       // (N, N, D)
    float* __restrict__ out)           // (B, N)
{
    const int b    = blockIdx.x;
    const int tid  = threadIdx.x;
    const int lane = tid & 63;
    const int wave = tid >> 6;            // 0..15

    const int node = idx[b];
    const float* __restrict__ Wb = W + (size_t)node * (NN * DD);

    __shared__ float e_lds[NN];           // 8 KB energies
    __shared__ float redm[16];
    __shared__ float reds[16];
    __shared__ float bm;
    __shared__ float bs;

    // Per-lane context fragment: 16 lanes x float4 cover all D=64.
    const float4 c = reinterpret_cast<const float4*>(ctx)[lane & 15];
    const int sub = lane >> 4;            // which of the 4 rows this wave-iter

    // Per-block phase stagger: all slabs are 512KB-aligned, so without this
    // all 256 CUs sweep HBM channels in lockstep. Rotate start by b*8 rows
    // (2KB). rot is a multiple of 8 so 4-row groups never straddle the wrap.
    const int rot = (b * 8) & (NN - 1);

    // ---- Phase 1: energies e[n] = dot(W[node,n,:], ctx), online max ----
    float mloc = -INFINITY;
    #pragma unroll 8
    for (int k = 0; k < NN / 64; ++k) {   // 32 iters, 4 rows/wave/iter
        const int r = 4 * (wave + 16 * k) + sub;
        const int p = (r + rot) & (NN - 1);
        const float4 v =
            reinterpret_cast<const float4*>(Wb + (size_t)p * DD)[lane & 15];
        float s = v.x * c.x + v.y * c.y + v.z * c.z + v.w * c.w;
        // butterfly reduce across the 16 lanes sharing this row:
        // afterwards ALL 16 lanes hold the row energy.
        s += __shfl_xor(s, 1);
        s += __shfl_xor(s, 2);
        s += __shfl_xor(s, 4);
        s += __shfl_xor(s, 8);
        mloc = fmaxf(mloc, s);
        if ((lane & 15) == 0) e_lds[p] = s;
    }
    // wave max (covers this wave's 128 rows)
    #pragma unroll
    for (int o = 32; o > 0; o >>= 1) mloc = fmaxf(mloc, __shfl_xor(mloc, o));
    if (lane == 0) redm[wave] = mloc;
    __syncthreads();

    // global max via wave 0
    if (wave == 0) {
        float t = redm[lane & 15];
        #pragma unroll
        for (int o = 8; o > 0; o >>= 1) t = fmaxf(t, __shfl_xor(t, o));
        if (lane == 0) bm = t;
    }
    __syncthreads();
    const float M = bm;

    // ---- Phase 2: exp + block sum + normalize ----
    const float x0 = __expf(e_lds[tid] - M);
    const float x1 = __expf(e_lds[tid + BLOCK] - M);
    float s = x0 + x1;
    #pragma unroll
    for (int o = 32; o > 0; o >>= 1) s += __shfl_xor(s, o);
    if (lane == 0) reds[wave] = s;
    __syncthreads();
    if (wave == 0) {
        float t = reds[lane & 15];
        #pragma unroll
        for (int o = 8; o > 0; o >>= 1) t += __shfl_xor(t, o);
        if (lane == 0) bs = t;
    }
    __syncthreads();
    const float inv = 1.0f / bs;

    float* __restrict__ orow = out + (size_t)b * NN;
    orow[tid]         = x0 * inv;
    orow[tid + BLOCK] = x1 * inv;
}

extern "C" void kernel_launch(void* const* d_in, const int* in_sizes, int n_in,
                              void* d_out, int out_size, void* d_ws, size_t ws_size,
                              hipStream_t stream) {
    const int*   idx = (const int*)d_in[0];    // node_indices (B,)
    const float* ctx = (const float*)d_in[1];  // context_vector (D,)
    const float* W   = (const float*)d_in[2];  // W (N,N,D)
    float*       out = (float*)d_out;          // (B, N)

    resonance_kernel<<<BB, BLOCK, 0, stream>>>(idx, ctx, W, out);
}